// Round 1
// baseline (6976.820 us; speedup 1.0000x reference)
//
#include <hip/hip_runtime.h>

// STA-LSTM forward: B=2048, S=128, D=64, H1=H2=128, OUT=1
// Phase 1: spatial-attention LSTM (recurrent, per-row), writes H to ws, alphas to out
// Phase 2: betas + h_att (batched per row, betas to out, h_att overwrites H in ws)
// Phase 3: temporal LSTM (recurrent), y_pred to out
// All phases in ONE kernel: 256 blocks x 256 threads, each block owns 8 batch rows.

#define BB 2048
#define SS 128
#define DD 64
#define HH 128
#define NG 512
#define M  8
#define NT 256

#define A_OFF    ((size_t)BB)
#define BETA_OFF ((size_t)BB + (size_t)SS*BB*DD)

__device__ __forceinline__ float sigf(float x){ return 1.0f/(1.0f + __expf(-x)); }
__device__ __forceinline__ float tanhx(float x){ return 1.0f - 2.0f/(1.0f + __expf(2.0f*x)); }

__device__ __forceinline__ float wmax64(float v){
#pragma unroll
  for (int m = 32; m; m >>= 1) v = fmaxf(v, __shfl_xor(v, m, 64));
  return v;
}
__device__ __forceinline__ float wsum64(float v){
#pragma unroll
  for (int m = 32; m; m >>= 1) v += __shfl_xor(v, m, 64);
  return v;
}

struct SM1 {              // phase 1: 30 KB
  float x[M][DD];
  float h[M][HH];
  float c[M][HH];
  float a[M][DD];
  float xw[M][DD];
  float g[M][NG];
};
struct SM2 {              // phase 2: 48 KB
  float A[32][HH];
  float tmp[32][SS];
  float bp[32][SS];
};
struct SM3 {              // phase 3: 28 KB
  float ha[M][HH];
  float lh[M][HH];
  float lc[M][HH];
  float g[M][NG];
  float yp[M];
};
union __align__(16) SMem { SM1 p1; SM2 p2; SM3 p3; };

__global__ __launch_bounds__(NT, 1) void sta_kernel(
    const float* __restrict__ X,
    const float* __restrict__ saW,  const float* __restrict__ saU,  const float* __restrict__ sab,
    const float* __restrict__ saWa, const float* __restrict__ saUa, const float* __restrict__ saba,
    const float* __restrict__ saVa,
    const float* __restrict__ taWa, const float* __restrict__ taba, const float* __restrict__ taVa,
    const float* __restrict__ taW,  const float* __restrict__ taU,  const float* __restrict__ tab,
    const float* __restrict__ taWy, const float* __restrict__ fcw,  const float* __restrict__ fcb,
    float* __restrict__ out, float* __restrict__ Hws)
{
  __shared__ SMem sm;
  const int tid = threadIdx.x;
  const int b0  = blockIdx.x * M;

  // ================= Phase 1: spatial-attention LSTM =================
  for (int idx = tid; idx < M*HH; idx += NT){
    int r = idx >> 7, j = idx & 127;
    sm.p1.h[r][j] = 0.f; sm.p1.c[r][j] = 0.f;
  }
  __syncthreads();

  for (int t = 0; t < SS; ++t){
    // load x_t (8 rows x 64)
    for (int idx = tid; idx < M*DD; idx += NT){
      int r = idx >> 6, d = idx & 63;
      sm.p1.x[r][d] = X[(size_t)(b0+r)*SS*DD + (size_t)t*DD + d];
    }
    __syncthreads();

    // a = tanh(x@saWa + [h,c]@saUa + saba)   (each wave: 2 rows, lanes = 64 cols)
    {
      const int col = tid & 63;
      const int r0 = (tid >> 6) * 2, r1 = r0 + 1;
      float a0 = saba[col], a1 = a0;
      for (int k = 0; k < DD; k += 4){
        float w[4];
#pragma unroll
        for (int i = 0; i < 4; ++i) w[i] = saWa[(k+i)*DD + col];
        float4 v0 = *(const float4*)&sm.p1.x[r0][k];
        float4 v1 = *(const float4*)&sm.p1.x[r1][k];
        a0 += w[0]*v0.x + w[1]*v0.y + w[2]*v0.z + w[3]*v0.w;
        a1 += w[0]*v1.x + w[1]*v1.y + w[2]*v1.z + w[3]*v1.w;
      }
      for (int k = 0; k < HH; k += 4){
        float w[4];
#pragma unroll
        for (int i = 0; i < 4; ++i) w[i] = saUa[(k+i)*DD + col];
        float4 v0 = *(const float4*)&sm.p1.h[r0][k];
        float4 v1 = *(const float4*)&sm.p1.h[r1][k];
        a0 += w[0]*v0.x + w[1]*v0.y + w[2]*v0.z + w[3]*v0.w;
        a1 += w[0]*v1.x + w[1]*v1.y + w[2]*v1.z + w[3]*v1.w;
      }
      for (int k = 0; k < HH; k += 4){
        float w[4];
#pragma unroll
        for (int i = 0; i < 4; ++i) w[i] = saUa[(HH+k+i)*DD + col];
        float4 v0 = *(const float4*)&sm.p1.c[r0][k];
        float4 v1 = *(const float4*)&sm.p1.c[r1][k];
        a0 += w[0]*v0.x + w[1]*v0.y + w[2]*v0.z + w[3]*v0.w;
        a1 += w[0]*v1.x + w[1]*v1.y + w[2]*v1.z + w[3]*v1.w;
      }
      sm.p1.a[r0][col] = tanhx(a0);
      sm.p1.a[r1][col] = tanhx(a1);
    }
    __syncthreads();

    // av = a@saVa ; alpha = softmax(av) ; xw = alpha*x ; write alphas
    {
      const int col = tid & 63;
      const int r0 = (tid >> 6) * 2, r1 = r0 + 1;
      float s0 = 0.f, s1 = 0.f;
      for (int k = 0; k < DD; k += 4){
        float w[4];
#pragma unroll
        for (int i = 0; i < 4; ++i) w[i] = saVa[(k+i)*DD + col];
        float4 v0 = *(const float4*)&sm.p1.a[r0][k];
        float4 v1 = *(const float4*)&sm.p1.a[r1][k];
        s0 += w[0]*v0.x + w[1]*v0.y + w[2]*v0.z + w[3]*v0.w;
        s1 += w[0]*v1.x + w[1]*v1.y + w[2]*v1.z + w[3]*v1.w;
      }
      float m0 = wmax64(s0), m1 = wmax64(s1);
      float e0 = __expf(s0 - m0), e1 = __expf(s1 - m1);
      float i0 = 1.0f / wsum64(e0), i1 = 1.0f / wsum64(e1);
      float al0 = e0 * i0, al1 = e1 * i1;
      out[A_OFF + (size_t)t*BB*DD + (size_t)(b0+r0)*DD + col] = al0;
      out[A_OFF + (size_t)t*BB*DD + (size_t)(b0+r1)*DD + col] = al1;
      sm.p1.xw[r0][col] = al0 * sm.p1.x[r0][col];
      sm.p1.xw[r1][col] = al1 * sm.p1.x[r1][col];
    }
    __syncthreads();

    // gates = xw@saW + h@saU + sab   (thread: cols {tid, tid+256}, all 8 rows)
    {
      const int c0 = tid, c1 = tid + NT;
      float acc0[M], acc1[M];
      const float bv0 = sab[c0], bv1 = sab[c1];
#pragma unroll
      for (int r = 0; r < M; ++r){ acc0[r] = bv0; acc1[r] = bv1; }
      for (int k = 0; k < DD; k += 4){
        float w0[4], w1[4];
#pragma unroll
        for (int i = 0; i < 4; ++i){ w0[i] = saW[(k+i)*NG + c0]; w1[i] = saW[(k+i)*NG + c1]; }
#pragma unroll
        for (int r = 0; r < M; ++r){
          float4 v = *(const float4*)&sm.p1.xw[r][k];
          acc0[r] += w0[0]*v.x + w0[1]*v.y + w0[2]*v.z + w0[3]*v.w;
          acc1[r] += w1[0]*v.x + w1[1]*v.y + w1[2]*v.z + w1[3]*v.w;
        }
      }
      for (int k = 0; k < HH; k += 4){
        float w0[4], w1[4];
#pragma unroll
        for (int i = 0; i < 4; ++i){ w0[i] = saU[(k+i)*NG + c0]; w1[i] = saU[(k+i)*NG + c1]; }
#pragma unroll
        for (int r = 0; r < M; ++r){
          float4 v = *(const float4*)&sm.p1.h[r][k];
          acc0[r] += w0[0]*v.x + w0[1]*v.y + w0[2]*v.z + w0[3]*v.w;
          acc1[r] += w1[0]*v.x + w1[1]*v.y + w1[2]*v.z + w1[3]*v.w;
        }
      }
#pragma unroll
      for (int r = 0; r < M; ++r){ sm.p1.g[r][c0] = acc0[r]; sm.p1.g[r][c1] = acc1[r]; }
    }
    __syncthreads();

    // LSTM pointwise update + store H
    for (int idx = tid; idx < M*HH; idx += NT){
      int r = idx >> 7, j = idx & 127;
      float iv = sigf (sm.p1.g[r][j]);
      float fv = sigf (sm.p1.g[r][j +   HH]);
      float gv = tanhx(sm.p1.g[r][j + 2*HH]);
      float ov = sigf (sm.p1.g[r][j + 3*HH]);
      float cn = fv * sm.p1.c[r][j] + iv * gv;
      float hn = ov * tanhx(cn);
      sm.p1.c[r][j] = cn; sm.p1.h[r][j] = hn;
      Hws[(size_t)(b0+r)*SS*HH + (size_t)t*HH + j] = hn;
    }
    __syncthreads();
  }

  // ================= Phase 2: betas + h_att (overwrites H in-place) =================
  for (int r = 0; r < M; ++r){
    float* Hrow = Hws + (size_t)(b0+r)*SS*HH;
    const int c  = tid & 127;
    const int th = tid >> 7;
    float hacc[64];
#pragma unroll
    for (int i = 0; i < 64; ++i) hacc[i] = 0.f;

#pragma unroll
    for (int ch = 0; ch < 4; ++ch){
      // stage 32 H rows into LDS
      for (int idx = tid; idx < 32*HH; idx += NT)
        ((float*)sm.p2.A)[idx] = Hrow[(size_t)ch*32*HH + idx];
      __syncthreads();

      // GEMM1: tmp = tanh(A @ taWa + taba)
      {
        float acc[16];
#pragma unroll
        for (int i = 0; i < 16; ++i) acc[i] = taba[c];
        for (int k = 0; k < HH; k += 4){
          float w[4];
#pragma unroll
          for (int i = 0; i < 4; ++i) w[i] = taWa[(k+i)*SS + c];
#pragma unroll
          for (int i = 0; i < 16; ++i){
            float4 v = *(const float4*)&sm.p2.A[th*16+i][k];
            acc[i] += w[0]*v.x + w[1]*v.y + w[2]*v.z + w[3]*v.w;
          }
        }
#pragma unroll
        for (int i = 0; i < 16; ++i) sm.p2.tmp[th*16+i][c] = tanhx(acc[i]);
      }
      __syncthreads();

      // GEMM2: bp = tmp @ taVa
      {
        float acc[16];
#pragma unroll
        for (int i = 0; i < 16; ++i) acc[i] = 0.f;
        for (int k = 0; k < SS; k += 4){
          float w[4];
#pragma unroll
          for (int i = 0; i < 4; ++i) w[i] = taVa[(k+i)*SS + c];
#pragma unroll
          for (int i = 0; i < 16; ++i){
            float4 v = *(const float4*)&sm.p2.tmp[th*16+i][k];
            acc[i] += w[0]*v.x + w[1]*v.y + w[2]*v.z + w[3]*v.w;
          }
        }
#pragma unroll
        for (int i = 0; i < 16; ++i) sm.p2.bp[th*16+i][c] = acc[i];
      }
      __syncthreads();

      // softmax rows of bp -> beta ; write betas out ; keep beta in LDS
      {
        const int wv = tid >> 6, lane = tid & 63;
#pragma unroll
        for (int it = 0; it < 8; ++it){
          int tl = wv + 4*it;
          float v0 = sm.p2.bp[tl][lane], v1 = sm.p2.bp[tl][lane+64];
          float mm = wmax64(fmaxf(v0, v1));
          float e0 = __expf(v0 - mm), e1 = __expf(v1 - mm);
          float inv = 1.0f / wsum64(e0 + e1);
          e0 *= inv; e1 *= inv;
          size_t bo = BETA_OFF + (size_t)(ch*32+tl)*BB*SS + (size_t)(b0+r)*SS;
          out[bo + lane]      = e0;
          out[bo + lane + 64] = e1;
          sm.p2.bp[tl][lane]      = e0;
          sm.p2.bp[tl][lane + 64] = e1;
        }
      }
      __syncthreads();

      // GEMM3: h_att(chunk rows) += beta @ Hrow   (Hrow streamed from L2)
      for (int k = 0; k < SS; k += 4){
        float hv[4];
#pragma unroll
        for (int j = 0; j < 4; ++j) hv[j] = Hrow[(size_t)(k+j)*HH + c];
#pragma unroll
        for (int i = 0; i < 16; ++i){
          float4 bv = *(const float4*)&sm.p2.bp[th*16+i][k];
          hacc[ch*16+i] += bv.x*hv[0] + bv.y*hv[1] + bv.z*hv[2] + bv.w*hv[3];
        }
      }
    }
    __syncthreads();   // all Hrow reads complete
#pragma unroll
    for (int ch = 0; ch < 4; ++ch)
#pragma unroll
      for (int i = 0; i < 16; ++i)
        Hrow[(size_t)(ch*32 + th*16 + i)*HH + c] = hacc[ch*16+i];
    __syncthreads();
  }

  // ================= Phase 3: temporal LSTM =================
  for (int idx = tid; idx < M*HH; idx += NT){
    int r = idx >> 7, j = idx & 127;
    sm.p3.lh[r][j] = 0.f; sm.p3.lc[r][j] = 0.f;
  }
  if (tid < M) sm.p3.yp[tid] = X[(size_t)(b0+tid)*SS*DD + (DD-1)];
  __syncthreads();

  for (int t = 0; t < SS; ++t){
    // stage h_att_t
    for (int idx = tid; idx < M*HH; idx += NT){
      int r = idx >> 7, j = idx & 127;
      sm.p3.ha[r][j] = Hws[(size_t)(b0+r)*SS*HH + (size_t)t*HH + j];
    }
    __syncthreads();

    // gates = h_att@taW + lh@taU + y_prev*taWy + tab
    {
      const int c0 = tid, c1 = tid + NT;
      const float wy0 = taWy[c0], wy1 = taWy[c1];
      const float tb0 = tab[c0],  tb1 = tab[c1];
      float acc0[M], acc1[M];
#pragma unroll
      for (int r = 0; r < M; ++r){
        float yp = sm.p3.yp[r];
        acc0[r] = tb0 + yp*wy0;
        acc1[r] = tb1 + yp*wy1;
      }
      for (int k = 0; k < HH; k += 4){
        float w0[4], w1[4];
#pragma unroll
        for (int i = 0; i < 4; ++i){ w0[i] = taW[(k+i)*NG + c0]; w1[i] = taW[(k+i)*NG + c1]; }
#pragma unroll
        for (int r = 0; r < M; ++r){
          float4 v = *(const float4*)&sm.p3.ha[r][k];
          acc0[r] += w0[0]*v.x + w0[1]*v.y + w0[2]*v.z + w0[3]*v.w;
          acc1[r] += w1[0]*v.x + w1[1]*v.y + w1[2]*v.z + w1[3]*v.w;
        }
      }
      for (int k = 0; k < HH; k += 4){
        float w0[4], w1[4];
#pragma unroll
        for (int i = 0; i < 4; ++i){ w0[i] = taU[(k+i)*NG + c0]; w1[i] = taU[(k+i)*NG + c1]; }
#pragma unroll
        for (int r = 0; r < M; ++r){
          float4 v = *(const float4*)&sm.p3.lh[r][k];
          acc0[r] += w0[0]*v.x + w0[1]*v.y + w0[2]*v.z + w0[3]*v.w;
          acc1[r] += w1[0]*v.x + w1[1]*v.y + w1[2]*v.z + w1[3]*v.w;
        }
      }
#pragma unroll
      for (int r = 0; r < M; ++r){ sm.p3.g[r][c0] = acc0[r]; sm.p3.g[r][c1] = acc1[r]; }
    }
    __syncthreads();

    // LSTM pointwise update
    for (int idx = tid; idx < M*HH; idx += NT){
      int r = idx >> 7, j = idx & 127;
      float iv = sigf (sm.p3.g[r][j]);
      float fv = sigf (sm.p3.g[r][j +   HH]);
      float gv = tanhx(sm.p3.g[r][j + 2*HH]);
      float ov = sigf (sm.p3.g[r][j + 3*HH]);
      float cn = fv * sm.p3.lc[r][j] + iv * gv;
      float hn = ov * tanhx(cn);
      sm.p3.lc[r][j] = cn; sm.p3.lh[r][j] = hn;
    }
    __syncthreads();

    // y = lh @ fc_w^T + fc_b  (32 lanes per row)
    {
      const int r = tid >> 5, l = tid & 31;
      float p = 0.f;
#pragma unroll
      for (int jj = 0; jj < HH; jj += 32) p += sm.p3.lh[r][l+jj] * fcw[l+jj];
#pragma unroll
      for (int m = 16; m; m >>= 1) p += __shfl_xor(p, m, 64);
      if (l == 0) sm.p3.yp[r] = p + fcb[0];
    }
    __syncthreads();
  }

  if (tid < M) out[b0 + tid] = sm.p3.yp[tid];
}

extern "C" void kernel_launch(void* const* d_in, const int* in_sizes, int n_in,
                              void* d_out, int out_size, void* d_ws, size_t ws_size,
                              hipStream_t stream) {
  (void)in_sizes; (void)n_in; (void)out_size; (void)ws_size;
  const float* X    = (const float*)d_in[0];
  const float* saW  = (const float*)d_in[1];
  const float* saU  = (const float*)d_in[2];
  const float* sab  = (const float*)d_in[3];
  const float* saWa = (const float*)d_in[4];
  const float* saUa = (const float*)d_in[5];
  const float* saba = (const float*)d_in[6];
  const float* saVa = (const float*)d_in[7];
  const float* taWa = (const float*)d_in[8];
  // d_in[9] = ta_Ua: unused by the reference forward pass
  const float* taba = (const float*)d_in[10];
  const float* taVa = (const float*)d_in[11];
  const float* taW  = (const float*)d_in[12];
  const float* taU  = (const float*)d_in[13];
  const float* tab  = (const float*)d_in[14];
  const float* taWy = (const float*)d_in[15];
  const float* fcw  = (const float*)d_in[16];
  const float* fcb  = (const float*)d_in[17];
  float* out = (float*)d_out;
  float* Hws = (float*)d_ws;   // B*S*H1 floats = 128 MB: H, overwritten by h_att in phase 2

  hipLaunchKernelGGL(sta_kernel, dim3(BB / M), dim3(NT), 0, stream,
                     X, saW, saU, sab, saWa, saUa, saba, saVa,
                     taWa, taba, taVa, taW, taU, tab, taWy, fcw, fcb,
                     out, Hws);
}